// Round 7
// baseline (1154.950 us; speedup 1.0000x reference)
//
#include <hip/hip_runtime.h>
#include <hip/hip_bf16.h>
#include <cmath>

#define N_NODES 8192
#define NFEAT 512
#define NHID 512
#define NCLASS 64
#define NLAYERS 8
#define CAP 96
#define NBLK 512

typedef __attribute__((ext_vector_type(8))) short bf16x8;
typedef __attribute__((ext_vector_type(4))) float f32x4;
typedef unsigned short u16;

struct Coefs { float cA[8]; float cB[8]; };

__device__ inline float bf2f(short u) {
  union { unsigned int i; float f; } x;
  x.i = ((unsigned int)(u16)u) << 16;
  return x.f;
}
__device__ inline short f2bf(float f) {
  union { float f; unsigned int i; } x;
  x.f = f;
  unsigned int r = x.i + 0x7FFFu + ((x.i >> 16) & 1u);
  return (short)(r >> 16);
}

// ---------------- adjacency extraction: one streaming pass over adj ----------
__global__ __launch_bounds__(256)
void extract_kernel(const float* __restrict__ adj, int* __restrict__ idx,
                    int* __restrict__ cnt, int* __restrict__ colcnt)
{
  __shared__ int s_cnt;
  const int i = blockIdx.x;
  if (threadIdx.x == 0) s_cnt = 0;
  __syncthreads();
  const uint4* row = (const uint4*)(adj + (size_t)i * N_NODES);
  for (int c = threadIdx.x; c < N_NODES / 4; c += 256) {
    uint4 v = row[c];
    if ((v.x | v.y | v.z | v.w) == 0u) continue;  // 0.0f bit pattern is 0
    unsigned int vals[4] = {v.x, v.y, v.z, v.w};
    #pragma unroll
    for (int e = 0; e < 4; ++e) {
      if (vals[e] != 0u) {
        int p = atomicAdd(&s_cnt, 1);
        if (p < CAP) idx[(size_t)i * CAP + p] = c * 4 + e;
        atomicAdd(&colcnt[c * 4 + e], 1);
      }
    }
  }
  __syncthreads();
  if (threadIdx.x == 0) cnt[i] = min(s_cnt, CAP);
}

// ---------------- device-scope grid barrier (512 co-resident blocks) --------
__device__ inline void gridbar(int* bar, int phase) {
  __syncthreads();
  if (threadIdx.x == 0) {
    __hip_atomic_fetch_add(&bar[phase], 1, __ATOMIC_RELEASE, __HIP_MEMORY_SCOPE_AGENT);
    while (__hip_atomic_load(&bar[phase], __ATOMIC_RELAXED, __HIP_MEMORY_SCOPE_AGENT) < NBLK)
      __builtin_amdgcn_s_sleep(1);
    __builtin_amdgcn_fence(__ATOMIC_ACQUIRE, "agent");
  }
  __syncthreads();
}

// ---------------- phase: dinv ------------------------------------------------
__device__ void p_dinv(const int* __restrict__ colc, float* __restrict__ dinv) {
  if (blockIdx.x < N_NODES / 256) {
    const int j = blockIdx.x * 256 + threadIdx.x;
    dinv[j] = 1.0f / sqrtf((float)colc[j] + 1.0f);  // +1 for identity
  }
}

// ---------------- phase: x -> bf16 ------------------------------------------
__device__ void p_cvt(const float* __restrict__ x, u16* __restrict__ xb) {
  const float4* src = (const float4*)x;
  #pragma unroll
  for (int it = 0; it < 8; ++it) {
    const int i = it * (NBLK * 256) + blockIdx.x * 256 + threadIdx.x;
    float4 v = src[i];
    ushort4 o;
    o.x = (u16)f2bf(v.x); o.y = (u16)f2bf(v.y);
    o.z = (u16)f2bf(v.z); o.w = (u16)f2bf(v.w);
    ((ushort4*)xb)[i] = o;
  }
}

// ---------------- phase: weight transpose + GCNII identity fold -------------
// Wt[0]=fc1W^T ; Wt[z]=cB*convW[z-1]^T + cA*I  (z=1..8)
__device__ void p_transpose(const float* __restrict__ fc1W, const float* __restrict__ convW,
                            u16* __restrict__ Wt, const Coefs& co, char* smem) {
  float (*tile)[33] = (float(*)[33])smem;
  const int tx = threadIdx.x & 31, ty = threadIdx.x >> 5;  // 32 x 8
  for (int it = 0; it < 5; ++it) {
    const int vb = it * NBLK + blockIdx.x;       // 0..2559, valid < 2304
    const bool valid = vb < 2304;
    int m = 0, k0 = 0, n0 = 0;
    const float* src = nullptr;
    u16* dst = nullptr;
    float cA = 0.f, cB = 1.f;
    if (valid) {
      m = vb >> 8; k0 = (vb & 15) * 32; n0 = ((vb >> 4) & 15) * 32;
      src = (m == 0) ? fc1W : convW + (size_t)(m - 1) * NHID * NHID;
      dst = Wt + (size_t)m * NHID * NHID;
      if (m >= 1) { cA = co.cA[m - 1]; cB = co.cB[m - 1]; }
      #pragma unroll
      for (int r = 0; r < 32; r += 8)
        tile[ty + r][tx] = src[(size_t)(k0 + ty + r) * NHID + n0 + tx];
    }
    __syncthreads();
    if (valid) {
      #pragma unroll
      for (int r = 0; r < 32; r += 8) {
        const int krow = k0 + tx, ncol = n0 + ty + r;
        float val = cB * tile[tx][ty + r];
        if (m >= 1 && krow == ncol) val += cA;
        dst[(size_t)ncol * NHID + krow] = (u16)f2bf(val);
      }
    }
    __syncthreads();
  }
}

// ---------------- phase: MFMA GEMM, BM=64 BN=128 BK=64, swizzled LDS --------
#define AS1 __attribute__((address_space(1)))
#define AS3 __attribute__((address_space(3)))

__device__ inline void load16(const void* g, void* l) {
  __builtin_amdgcn_global_load_lds((const AS1 void*)g, (AS3 void*)l, 16, 0, 0);
}

// 512 blocks: mblk = bid&127 (64-row A panel, XCD = mblk%8), nblk = bid>>7.
// Per wave: 64x32 out (4 A-frags x 2 B-frags -> 0.75 KB LDS per MFMA).
// mode 0: v=relu(acc+bias); out0=H0, out1=Hs=dinv*v   [fc1]
// mode 1: v=relu(acc);      out0=Hs=dinv*v            [layers 0..6]
// mode 2: v=relu(acc);      out0=H (unscaled)         [layer 7]
__device__ void gemm_phase(const u16* __restrict__ A, const u16* __restrict__ Bt,
                           const float* __restrict__ bias, const float* __restrict__ dinv,
                           u16* __restrict__ out0, u16* __restrict__ out1,
                           int mode, char* smem)
{
  constexpr int K = 512, N = 512;
  u16* ldsA = (u16*)smem;               // [2][64*64]   16 KB
  u16* ldsB = (u16*)(smem + 16384);     // [2][128*64]  32 KB
  const int tid = threadIdx.x;
  const int wave = tid >> 6, lane = tid & 63;
  const int m0 = (blockIdx.x & 127) * 64;
  const int n0 = (blockIdx.x >> 7) * 128;
  const int lrow = lane & 15, lk = lane >> 4;

  f32x4 acc[4][2];
  #pragma unroll
  for (int a = 0; a < 4; ++a)
    #pragma unroll
    for (int b = 0; b < 2; ++b)
      acc[a][b] = (f32x4){0.f, 0.f, 0.f, 0.f};

  // rows are 64 k = 128 B = 8 chunks of 16 B; XOR swizzle j^(row&7) applied on
  // the per-lane GLOBAL source chunk, LDS dest linear (both-sides rule).
  auto stage = [&](int b, int ks) {
    #pragma unroll
    for (int r = 0; r < 2; ++r) {              // A: 512 chunks
      const int c = r * 256 + wave * 64 + lane;
      const int row = c >> 3, sc = (c & 7) ^ (row & 7);
      load16(A + (size_t)(m0 + row) * K + ks + sc * 8,
             &ldsA[b * 4096 + (r * 256 + wave * 64) * 8]);
    }
    #pragma unroll
    for (int r = 0; r < 4; ++r) {              // B: 1024 chunks
      const int c = r * 256 + wave * 64 + lane;
      const int row = c >> 3, sc = (c & 7) ^ (row & 7);
      load16(Bt + (size_t)(n0 + row) * K + ks + sc * 8,
             &ldsB[b * 8192 + (r * 256 + wave * 64) * 8]);
    }
  };

  stage(0, 0);
  __syncthreads();

  for (int t = 0; t < K / 64; ++t) {
    const int b = t & 1;
    if (t + 1 < K / 64) stage(b ^ 1, (t + 1) * 64);   // prefetch under MFMA
    const char* pA = (const char*)(ldsA + b * 4096);
    const char* pB = (const char*)(ldsB + b * 8192);
    #pragma unroll
    for (int ks2 = 0; ks2 < 2; ++ks2) {
      const int j = ks2 * 4 + lk;
      bf16x8 af[4], bfr[2];
      #pragma unroll
      for (int mi = 0; mi < 4; ++mi) {
        const int row = mi * 16 + lrow;
        af[mi] = *(const bf16x8*)(pA + row * 128 + ((j ^ (row & 7)) * 16));
      }
      #pragma unroll
      for (int ni = 0; ni < 2; ++ni) {
        const int row = wave * 32 + ni * 16 + lrow;
        bfr[ni] = *(const bf16x8*)(pB + row * 128 + ((j ^ (row & 7)) * 16));
      }
      #pragma unroll
      for (int mi = 0; mi < 4; ++mi)
        #pragma unroll
        for (int ni = 0; ni < 2; ++ni)
          acc[mi][ni] = __builtin_amdgcn_mfma_f32_16x16x32_bf16(af[mi], bfr[ni], acc[mi][ni], 0, 0, 0);
    }
    __syncthreads();
  }

  #pragma unroll
  for (int mi = 0; mi < 4; ++mi) {
    #pragma unroll
    for (int ni = 0; ni < 2; ++ni) {
      #pragma unroll
      for (int r = 0; r < 4; ++r) {
        const int row = m0 + mi * 16 + lk * 4 + r;
        const int col = n0 + wave * 32 + ni * 16 + lrow;
        const size_t o = (size_t)row * N + col;
        float v = acc[mi][ni][r];
        if (mode == 0) {
          v = fmaxf(v + bias[col], 0.f);
          out0[o] = (u16)f2bf(v);                 // H0
          out1[o] = (u16)f2bf(dinv[row] * v);     // Hs
        } else {
          v = fmaxf(v, 0.f);
          out0[o] = (u16)f2bf(mode == 1 ? dinv[row] * v : v);
        }
      }
    }
  }
}

// ---------------- phase: SpMM, IR = 0.9*(P@H) + 0.1*H0 ----------------------
// Row ownership XCD-aligned to gemm A-panels: panel p served by a block with
// bid%8 == p%8, so IR writes are L2-local for the GEMM that reads them.
__device__ void spmm_phase(const u16* __restrict__ Hs, const u16* __restrict__ H0,
                           const float* __restrict__ dinv, const int* __restrict__ idx,
                           const int* __restrict__ cnt, u16* __restrict__ IR)
{
  const int wave = threadIdx.x >> 6, lane = threadIdx.x & 63;
  const int xcd = blockIdx.x & 7, q = blockIdx.x >> 3;
  const int p = xcd + 8 * (q >> 2);              // panel 0..127, p%8 == bid%8
  const int row0 = p * 64 + (q & 3) * 16 + wave * 4;
  const int c0 = lane * 8;
  for (int rr = 0; rr < 4; ++rr) {
    const int i = row0 + rr;
    const int n = cnt[i];
    int jreg = 0;
    if (lane < n) jreg = idx[(size_t)i * CAP + lane] & (N_NODES - 1);
    float acc[8];
    #pragma unroll
    for (int e = 0; e < 8; ++e) acc[e] = 0.f;
    const int nn = min(n, 64);
    int t = 0;
    for (; t + 8 <= nn; t += 8) {                // 8 gathers in flight
      bf16x8 v[8];
      #pragma unroll
      for (int u = 0; u < 8; ++u) {
        const int j = __shfl(jreg, t + u);
        v[u] = *(const bf16x8*)&Hs[(size_t)j * NHID + c0];
      }
      #pragma unroll
      for (int u = 0; u < 8; ++u)
        #pragma unroll
        for (int e = 0; e < 8; ++e)
          acc[e] += bf2f(v[u][e]);
    }
    for (; t < nn; ++t) {
      const int j = __shfl(jreg, t);
      bf16x8 v = *(const bf16x8*)&Hs[(size_t)j * NHID + c0];
      #pragma unroll
      for (int e = 0; e < 8; ++e) acc[e] += bf2f(v[e]);
    }
    for (; t < n; ++t) {                         // n > 64: essentially never
      const int j = idx[(size_t)i * CAP + t] & (N_NODES - 1);
      bf16x8 v = *(const bf16x8*)&Hs[(size_t)j * NHID + c0];
      #pragma unroll
      for (int e = 0; e < 8; ++e) acc[e] += bf2f(v[e]);
    }
    const float di = dinv[i];
    bf16x8 self = *(const bf16x8*)&Hs[(size_t)i * NHID + c0];
    bf16x8 h0   = *(const bf16x8*)&H0[(size_t)i * NHID + c0];
    bf16x8 ov;
    #pragma unroll
    for (int e = 0; e < 8; ++e) {
      float v = 0.9f * di * (acc[e] + bf2f(self[e])) + 0.1f * bf2f(h0[e]);
      ov[e] = f2bf(v);
    }
    *(bf16x8*)&IR[(size_t)i * NHID + c0] = ov;
  }
}

// ---------------- phase: fc2 + -log_softmax ---------------------------------
__device__ void fc2_phase(const u16* __restrict__ H, const float* __restrict__ W,
                          const float* __restrict__ b, float* __restrict__ out,
                          char* smem)
{
  float (*sh)[4][512] = (float(*)[4][512])smem;  // [4][4][512] = 32 KB
  const int wave = threadIdx.x >> 6, lane = threadIdx.x & 63;
  const int rowBase = blockIdx.x * 16 + wave * 4;
  #pragma unroll
  for (int rr = 0; rr < 4; ++rr) {
    bf16x8 hv = *(const bf16x8*)&H[(size_t)(rowBase + rr) * NHID + lane * 8];
    #pragma unroll
    for (int e = 0; e < 8; ++e) sh[wave][rr][lane * 8 + e] = bf2f(hv[e]);
  }
  __syncthreads();
  const float bb = b[lane];
  float a0 = bb, a1 = bb, a2 = bb, a3 = bb;
  #pragma unroll 8
  for (int k = 0; k < 512; ++k) {
    const float w = W[k * 64 + lane];
    a0 += sh[wave][0][k] * w;
    a1 += sh[wave][1][k] * w;
    a2 += sh[wave][2][k] * w;
    a3 += sh[wave][3][k] * w;
  }
  float accs[4] = {a0, a1, a2, a3};
  #pragma unroll
  for (int rr = 0; rr < 4; ++rr) {
    const float v = accs[rr];
    float mx = v;
    #pragma unroll
    for (int off = 32; off > 0; off >>= 1) mx = fmaxf(mx, __shfl_xor(mx, off));
    float s = __expf(v - mx);
    #pragma unroll
    for (int off = 32; off > 0; off >>= 1) s += __shfl_xor(s, off);
    out[(size_t)(rowBase + rr) * NCLASS + lane] = -(v - mx - logf(s));
  }
}

// ---------------- the persistent kernel --------------------------------------
__global__ __launch_bounds__(256, 2)
void mega_kernel(const float* __restrict__ x, const float* __restrict__ fc1W,
                 const float* __restrict__ fc1b, const float* __restrict__ convW,
                 const float* __restrict__ fc2W, const float* __restrict__ fc2b,
                 const int* __restrict__ colc, const int* __restrict__ idx,
                 const int* __restrict__ cnt,
                 u16* __restrict__ xb, u16* __restrict__ Wt, float* __restrict__ dinv,
                 u16* __restrict__ H0, u16* __restrict__ HsA, u16* __restrict__ HsB,
                 u16* __restrict__ IR, float* __restrict__ out,
                 int* __restrict__ bar, Coefs co)
{
  __shared__ char smem[49152];   // 48 KB: gemm 2x(16+32)KB / transpose 4.2KB / fc2 32KB

  // phase 0: prep (all independent, whole grid)
  p_dinv(colc, dinv);
  p_cvt(x, xb);
  p_transpose(fc1W, convW, Wt, co, smem);
  gridbar(bar, 0);

  // fc1: H0 = relu(x@W+b), Hs = dinv*H0
  gemm_phase(xb, Wt, fc1b, dinv, H0, HsA, 0, smem);
  gridbar(bar, 1);

  const u16* Hin = HsA;
  for (int l = 0; l < NLAYERS; ++l) {
    spmm_phase(Hin, H0, dinv, idx, cnt, IR);
    gridbar(bar, 2 + 2 * l);
    u16* Hout = (l & 1) ? HsA : HsB;
    gemm_phase(IR, Wt + (size_t)(l + 1) * NHID * NHID, nullptr, dinv,
               Hout, nullptr, (l < NLAYERS - 1) ? 1 : 2, smem);
    gridbar(bar, 3 + 2 * l);
    Hin = Hout;
  }

  fc2_phase(Hin, fc2W, fc2b, out, smem);
}

// ---------------- launch -----------------------------------------------------
extern "C" void kernel_launch(void* const* d_in, const int* in_sizes, int n_in,
                              void* d_out, int out_size, void* d_ws, size_t ws_size,
                              hipStream_t stream)
{
  const float* x     = (const float*)d_in[0];
  const float* adj   = (const float*)d_in[1];
  const float* fc1W  = (const float*)d_in[2];
  const float* fc1b  = (const float*)d_in[3];
  const float* convW = (const float*)d_in[4];
  const float* fc2W  = (const float*)d_in[5];
  const float* fc2b  = (const float*)d_in[6];
  float* out = (float*)d_out;

  char* ws = (char*)d_ws;
  size_t off = 0;
  auto alloc = [&](size_t bytes) -> void* {
    void* p = ws + off;
    off = (off + bytes + 255) & ~(size_t)255;
    return p;
  };
  u16*   xb   = (u16*)alloc((size_t)N_NODES * NFEAT * 2);
  u16*   Wt   = (u16*)alloc((size_t)9 * NHID * NHID * 2);
  u16*   H0   = (u16*)alloc((size_t)N_NODES * NHID * 2);
  u16*   HsA  = (u16*)alloc((size_t)N_NODES * NHID * 2);
  u16*   HsB  = (u16*)alloc((size_t)N_NODES * NHID * 2);
  u16*   IR   = (u16*)alloc((size_t)N_NODES * NHID * 2);
  int*   idx  = (int*)alloc((size_t)N_NODES * CAP * 4);
  int*   cnt  = (int*)alloc((size_t)N_NODES * 4);
  float* dinv = (float*)alloc((size_t)N_NODES * 4);
  int*   colc = (int*)alloc((size_t)N_NODES * 4);   // colc + bar zeroed together
  int*   bar  = (int*)alloc(128);

  Coefs co;
  for (int i = 0; i < NLAYERS; ++i) {
    const double beta = log(0.5 / (double)(i + 1) + 1.0);
    co.cA[i] = (float)(1.0 - beta);
    co.cB[i] = (float)beta;
  }

  hipMemsetAsync(colc, 0, (size_t)N_NODES * 4 + 128, stream);
  extract_kernel<<<N_NODES, 256, 0, stream>>>(adj, idx, cnt, colc);
  mega_kernel<<<NBLK, 256, 0, stream>>>(x, fc1W, fc1b, convW, fc2W, fc2b,
                                        colc, idx, cnt, xb, Wt, dinv,
                                        H0, HsA, HsB, IR, out, bar, co);
}

// Round 8
// 308.244 us; speedup vs baseline: 3.7469x; 3.7469x over previous
//
#include <hip/hip_runtime.h>
#include <hip/hip_bf16.h>
#include <cmath>

#define N_NODES 8192
#define NFEAT 512
#define NHID 512
#define NCLASS 64
#define NLAYERS 8
#define CAP 96

typedef __attribute__((ext_vector_type(8))) short bf16x8;
typedef __attribute__((ext_vector_type(4))) float f32x4;
typedef unsigned short u16;

struct Coefs { float cA[8]; float cB[8]; };

__device__ inline float bf2f(short u) {
  union { unsigned int i; float f; } x;
  x.i = ((unsigned int)(u16)u) << 16;
  return x.f;
}
__device__ inline short f2bf(float f) {
  union { float f; unsigned int i; } x;
  x.f = f;
  unsigned int r = x.i + 0x7FFFu + ((x.i >> 16) & 1u);
  return (short)(r >> 16);
}

// ---------------- front: extract || x->bf16 || weight transpose --------------
// blocks [0,8192): adjacency extraction (HBM-bound, 256 MB)
// blocks [8192,9216): x f32->bf16 (16 MB)
// blocks [9216,11776): weight transpose + GCNII identity fold (9.4 MB)
// The small jobs hide under the extract's HBM time.
__global__ __launch_bounds__(256)
void front_kernel(const float* __restrict__ adj, int* __restrict__ idx,
                  int* __restrict__ cnt, int* __restrict__ colcnt,
                  const float* __restrict__ x, u16* __restrict__ xb,
                  const float* __restrict__ fc1W, const float* __restrict__ convW,
                  const float* __restrict__ fc2W,
                  u16* __restrict__ Wt, u16* __restrict__ Wt2, Coefs co)
{
  __shared__ char smraw[4224];
  const int bid = blockIdx.x;

  if (bid < 8192) {                    // ---- extract row bid ----
    int* s_cnt = (int*)smraw;
    const int i = bid;
    if (threadIdx.x == 0) *s_cnt = 0;
    __syncthreads();
    const uint4* row = (const uint4*)(adj + (size_t)i * N_NODES);
    for (int c = threadIdx.x; c < N_NODES / 4; c += 256) {
      uint4 v = row[c];
      if ((v.x | v.y | v.z | v.w) == 0u) continue;   // 0.0f bit pattern is 0
      unsigned int vals[4] = {v.x, v.y, v.z, v.w};
      #pragma unroll
      for (int e = 0; e < 4; ++e) {
        if (vals[e] != 0u) {
          int p = atomicAdd(s_cnt, 1);
          if (p < CAP) idx[(size_t)i * CAP + p] = c * 4 + e;
          atomicAdd(&colcnt[c * 4 + e], 1);
        }
      }
    }
    __syncthreads();
    if (threadIdx.x == 0) cnt[i] = min(*s_cnt, CAP);
    return;
  }

  if (bid < 9216) {                    // ---- x -> bf16 ----
    const int base = (bid - 8192) * 256 + threadIdx.x;
    const float4* src = (const float4*)x;
    #pragma unroll
    for (int it = 0; it < 4; ++it) {
      const int i = it * (1024 * 256) + base;
      float4 v = src[i];
      ushort4 o;
      o.x = (u16)f2bf(v.x); o.y = (u16)f2bf(v.y);
      o.z = (u16)f2bf(v.z); o.w = (u16)f2bf(v.w);
      ((ushort4*)xb)[i] = o;
    }
    return;
  }

  // ---- weight transpose + identity fold ----
  // vb in [0,2560): m = vb>>8 (0=fc1, 1..8=conv layer, 9=fc2)
  float (*tile)[33] = (float(*)[33])smraw;
  const int vb = bid - 9216;
  const int m = vb >> 8;
  const int k0 = (vb & 15) * 32, n0 = ((vb >> 4) & 15) * 32;
  if (m == 9 && n0 >= 64) return;
  const int tx = threadIdx.x & 31, ty = threadIdx.x >> 5;  // 32 x 8
  if (m == 9) {
    #pragma unroll
    for (int r = 0; r < 32; r += 8)
      tile[ty + r][tx] = fc2W[(size_t)(k0 + ty + r) * 64 + n0 + tx];
    __syncthreads();
    #pragma unroll
    for (int r = 0; r < 32; r += 8)
      Wt2[(size_t)(n0 + ty + r) * 512 + k0 + tx] = (u16)f2bf(tile[tx][ty + r]);
    return;
  }
  const float* src = (m == 0) ? fc1W : convW + (size_t)(m - 1) * NHID * NHID;
  u16* dst = Wt + (size_t)m * NHID * NHID;
  float cA = 0.f, cB = 1.f;
  if (m >= 1) { cA = co.cA[m - 1]; cB = co.cB[m - 1]; }
  #pragma unroll
  for (int r = 0; r < 32; r += 8)
    tile[ty + r][tx] = src[(size_t)(k0 + ty + r) * NHID + n0 + tx];
  __syncthreads();
  #pragma unroll
  for (int r = 0; r < 32; r += 8) {
    const int krow = k0 + tx, ncol = n0 + ty + r;
    float val = cB * tile[tx][ty + r];
    if (m >= 1 && krow == ncol) val += cA;
    dst[(size_t)ncol * NHID + krow] = (u16)f2bf(val);
  }
}

// ---------------- MFMA GEMM, 64x64 tile, BK=64, 3-buf depth-2 pipeline ------
#define AS1 __attribute__((address_space(1)))
#define AS3 __attribute__((address_space(3)))

__device__ inline void load16(const void* g, void* l) {
  __builtin_amdgcn_global_load_lds((const AS1 void*)g, (AS3 void*)l, 16, 0, 0);
}

// MODE 0: v=relu(acc+bias); out0=H0, out1=Hs=dinv*v       [fc1]
// MODE 1: v=relu(acc);      out0=Hs=dinv*v                [layers 0..6]
// MODE 2: v=relu(acc);      out0=H (unscaled)             [layer 7]
// MODE 3: logits=acc+bias -> -log_softmax -> outF (f32)   [fc2, N=64]
// dinv computed inline as rsqrt(colc+1).
// Pipeline: 3 LDS buffers, depth-2 prefetch. Per step: counted
// s_waitcnt vmcnt(4) (own stage(t) drained; stage(t+1) stays in flight)
// + raw s_barrier (all waves' stage(t) done), THEN issue stage(t+2)
// (its target buffer (t+2)%3 == (t-1)%3 was last read in compute(t-1),
// which every wave finished before this barrier), then compute(t).
template<int MODE>
__global__ __launch_bounds__(256, 3)
void gemm_kernel(const u16* __restrict__ A, const u16* __restrict__ Bt,
                 const float* __restrict__ bias, const int* __restrict__ colc,
                 u16* __restrict__ out0, u16* __restrict__ out1,
                 float* __restrict__ outF)
{
  constexpr int K = 512;
  constexpr int N = (MODE == 3) ? NCLASS : 512;
  __shared__ u16 lds[3][2][64 * 64];   // [buf][A/B][tile] = 48 KB
  const int tid = threadIdx.x;
  const int wave = tid >> 6, lane = tid & 63;

  // chunked XCD swizzle (same-A-panel blocks share an XCD's L2)
  const int cpx = gridDim.x >> 3;
  const int logical = (blockIdx.x & 7) * cpx + (blockIdx.x >> 3);
  const int mblk = (MODE == 3) ? logical : (logical >> 3);
  const int nblk = (MODE == 3) ? 0 : (logical & 7);
  const int m0 = mblk * 64, n0 = nblk * 64;

  const int wr = wave >> 1, wc = wave & 1;
  const int lrow = lane & 15, lk = lane >> 4;

  f32x4 acc[2][2];
  #pragma unroll
  for (int a = 0; a < 2; ++a)
    #pragma unroll
    for (int b = 0; b < 2; ++b)
      acc[a][b] = (f32x4){0.f, 0.f, 0.f, 0.f};

  // rows of 64 k = 128 B = 8 chunks of 16 B; XOR swizzle j^(row&7) folded into
  // the per-lane GLOBAL source chunk, LDS dest linear (both-sides rule).
  auto stage = [&](int b, int ks) {
    #pragma unroll
    for (int r = 0; r < 2; ++r) {
      const int c = r * 256 + wave * 64 + lane;   // 512 chunks of 16B per tile
      const int row = c >> 3;
      const int sc = (c & 7) ^ (row & 7);
      load16(A  + (size_t)(m0 + row) * K + ks + sc * 8, &lds[b][0][(r * 256 + wave * 64) * 8]);
      load16(Bt + (size_t)(n0 + row) * K + ks + sc * 8, &lds[b][1][(r * 256 + wave * 64) * 8]);
    }
  };

  stage(0, 0);
  stage(1, 64);

  for (int t = 0; t < 8; ++t) {
    if (t < 7) asm volatile("s_waitcnt vmcnt(4)\n\ts_barrier" ::: "memory");
    else       asm volatile("s_waitcnt vmcnt(0)\n\ts_barrier" ::: "memory");
    if (t + 2 < 8) stage((t + 2) % 3, (t + 2) * 64);
    const int b = t % 3;
    const char* pA = (const char*)lds[b][0];
    const char* pB = (const char*)lds[b][1];
    bf16x8 af[2][2], bfr[2][2];
    #pragma unroll
    for (int mi = 0; mi < 2; ++mi) {
      const int row = wr * 32 + mi * 16 + lrow;
      #pragma unroll
      for (int ks2 = 0; ks2 < 2; ++ks2) {
        const int j = ks2 * 4 + lk;
        af[mi][ks2] = *(const bf16x8*)(pA + row * 128 + ((j ^ (row & 7)) * 16));
      }
    }
    #pragma unroll
    for (int ni = 0; ni < 2; ++ni) {
      const int row = wc * 32 + ni * 16 + lrow;
      #pragma unroll
      for (int ks2 = 0; ks2 < 2; ++ks2) {
        const int j = ks2 * 4 + lk;
        bfr[ni][ks2] = *(const bf16x8*)(pB + row * 128 + ((j ^ (row & 7)) * 16));
      }
    }
    #pragma unroll
    for (int ks2 = 0; ks2 < 2; ++ks2)
      #pragma unroll
      for (int mi = 0; mi < 2; ++mi)
        #pragma unroll
        for (int ni = 0; ni < 2; ++ni)
          acc[mi][ni] = __builtin_amdgcn_mfma_f32_16x16x32_bf16(af[mi][ks2], bfr[ni][ks2], acc[mi][ni], 0, 0, 0);
  }

  if (MODE != 3) {
    #pragma unroll
    for (int mi = 0; mi < 2; ++mi) {
      #pragma unroll
      for (int ni = 0; ni < 2; ++ni) {
        #pragma unroll
        for (int r = 0; r < 4; ++r) {
          const int row = m0 + wr * 32 + mi * 16 + lk * 4 + r;
          const int col = n0 + wc * 32 + ni * 16 + lrow;
          const size_t o = (size_t)row * N + col;
          float v = acc[mi][ni][r];
          if (MODE == 0) {
            v = fmaxf(v + bias[col], 0.f);
            const float di = rsqrtf((float)colc[row] + 1.0f);
            out0[o] = (u16)f2bf(v);                 // H0
            out1[o] = (u16)f2bf(di * v);            // Hs
          } else if (MODE == 1) {
            v = fmaxf(v, 0.f);
            const float di = rsqrtf((float)colc[row] + 1.0f);
            out0[o] = (u16)f2bf(di * v);
          } else {
            v = fmaxf(v, 0.f);
            out0[o] = (u16)f2bf(v);
          }
        }
      }
    }
  } else {
    __syncthreads();
    // stash logits (+bias) in LDS, then per-row softmax with lane = class
    float* Cf = (float*)&lds[0][0][0];              // 64x65 f32
    #pragma unroll
    for (int mi = 0; mi < 2; ++mi)
      #pragma unroll
      for (int ni = 0; ni < 2; ++ni)
        #pragma unroll
        for (int r = 0; r < 4; ++r) {
          const int row = wr * 32 + mi * 16 + lk * 4 + r;
          const int cc = wc * 32 + ni * 16 + lrow;
          if (cc < NCLASS) Cf[row * 65 + cc] = acc[mi][ni][r] + bias[cc];
        }
    __syncthreads();
    #pragma unroll 4
    for (int r = 0; r < 16; ++r) {
      const int row = wave * 16 + r;
      const float v = Cf[row * 65 + lane];
      float mx = v;
      #pragma unroll
      for (int off = 32; off > 0; off >>= 1) mx = fmaxf(mx, __shfl_xor(mx, off));
      float s = __expf(v - mx);
      #pragma unroll
      for (int off = 32; off > 0; off >>= 1) s += __shfl_xor(s, off);
      outF[(size_t)(m0 + row) * NCLASS + lane] = -(v - mx - logf(s));
    }
  }
}

// ---------------- SpMM: IR = 0.9*(P@H) + 0.1*H0, H pre-scaled ---------------
__global__ __launch_bounds__(256)
void spmm_kernel(const u16* __restrict__ Hs, const u16* __restrict__ H0,
                 const int* __restrict__ colc, const int* __restrict__ idx,
                 const int* __restrict__ cnt, u16* __restrict__ IR)
{
  const int wave = threadIdx.x >> 6, lane = threadIdx.x & 63;
  const int i = blockIdx.x * 4 + wave;
  const int c0 = lane * 8;
  const int n = cnt[i];
  int jreg = 0;
  if (lane < n) jreg = idx[(size_t)i * CAP + lane] & (N_NODES - 1);

  float acc[8];
  #pragma unroll
  for (int e = 0; e < 8; ++e) acc[e] = 0.f;

  const int nn = min(n, 64);
  int t = 0;
  for (; t + 8 <= nn; t += 8) {          // 8 gathers in flight
    bf16x8 v[8];
    #pragma unroll
    for (int u = 0; u < 8; ++u) {
      const int j = __shfl(jreg, t + u);
      v[u] = *(const bf16x8*)&Hs[(size_t)j * NHID + c0];
    }
    #pragma unroll
    for (int u = 0; u < 8; ++u)
      #pragma unroll
      for (int e = 0; e < 8; ++e)
        acc[e] += bf2f(v[u][e]);
  }
  for (; t < nn; ++t) {
    const int j = __shfl(jreg, t);
    bf16x8 v = *(const bf16x8*)&Hs[(size_t)j * NHID + c0];
    #pragma unroll
    for (int e = 0; e < 8; ++e) acc[e] += bf2f(v[e]);
  }
  for (; t < n; ++t) {                   // n > 64: essentially never
    const int j = idx[(size_t)i * CAP + t] & (N_NODES - 1);
    bf16x8 v = *(const bf16x8*)&Hs[(size_t)j * NHID + c0];
    #pragma unroll
    for (int e = 0; e < 8; ++e) acc[e] += bf2f(v[e]);
  }

  const float di = rsqrtf((float)colc[i] + 1.0f);
  bf16x8 self = *(const bf16x8*)&Hs[(size_t)i * NHID + c0];
  bf16x8 h0   = *(const bf16x8*)&H0[(size_t)i * NHID + c0];
  bf16x8 ov;
  #pragma unroll
  for (int e = 0; e < 8; ++e) {
    float v = 0.9f * di * (acc[e] + bf2f(self[e])) + 0.1f * bf2f(h0[e]);
    ov[e] = f2bf(v);
  }
  *(bf16x8*)&IR[(size_t)i * NHID + c0] = ov;
}

// ---------------- launch -----------------------------------------------------
extern "C" void kernel_launch(void* const* d_in, const int* in_sizes, int n_in,
                              void* d_out, int out_size, void* d_ws, size_t ws_size,
                              hipStream_t stream)
{
  const float* x     = (const float*)d_in[0];
  const float* adj   = (const float*)d_in[1];
  const float* fc1W  = (const float*)d_in[2];
  const float* fc1b  = (const float*)d_in[3];
  const float* convW = (const float*)d_in[4];
  const float* fc2W  = (const float*)d_in[5];
  const float* fc2b  = (const float*)d_in[6];
  float* out = (float*)d_out;

  char* ws = (char*)d_ws;
  size_t off = 0;
  auto alloc = [&](size_t bytes) -> void* {
    void* p = ws + off;
    off = (off + bytes + 255) & ~(size_t)255;
    return p;
  };
  u16*   xb   = (u16*)alloc((size_t)N_NODES * NFEAT * 2);
  u16*   Wt   = (u16*)alloc((size_t)9 * NHID * NHID * 2);
  u16*   Wt2  = (u16*)alloc((size_t)NCLASS * NHID * 2);
  u16*   H0   = (u16*)alloc((size_t)N_NODES * NHID * 2);
  u16*   HsA  = (u16*)alloc((size_t)N_NODES * NHID * 2);
  u16*   HsB  = (u16*)alloc((size_t)N_NODES * NHID * 2);
  u16*   IR   = (u16*)alloc((size_t)N_NODES * NHID * 2);
  int*   idx  = (int*)alloc((size_t)N_NODES * CAP * 4);
  int*   cnt  = (int*)alloc((size_t)N_NODES * 4);
  int*   colc = (int*)alloc((size_t)N_NODES * 4);

  Coefs co;
  for (int i = 0; i < NLAYERS; ++i) {
    const double beta = log(0.5 / (double)(i + 1) + 1.0);
    co.cA[i] = (float)(1.0 - beta);
    co.cB[i] = (float)beta;
  }

  hipMemsetAsync(colc, 0, (size_t)N_NODES * 4, stream);
  front_kernel<<<8192 + 1024 + 2560, 256, 0, stream>>>(
      adj, idx, cnt, colc, x, xb, fc1W, convW, fc2W, Wt, Wt2, co);

  // fc1: H0 = relu(x@W+b), Hs = dinv*H0
  gemm_kernel<0><<<1024, 256, 0, stream>>>(xb, Wt, fc1b, colc, H0, HsA, nullptr);

  const u16* Hin = HsA;
  for (int i = 0; i < NLAYERS; ++i) {
    spmm_kernel<<<N_NODES / 4, 256, 0, stream>>>(Hin, H0, colc, idx, cnt, IR);
    u16* Hout = (Hin == HsA) ? HsB : HsA;
    if (i < NLAYERS - 1)
      gemm_kernel<1><<<1024, 256, 0, stream>>>(
          IR, Wt + (size_t)(i + 1) * NHID * NHID, nullptr, colc, Hout, nullptr, nullptr);
    else
      gemm_kernel<2><<<1024, 256, 0, stream>>>(
          IR, Wt + (size_t)(i + 1) * NHID * NHID, nullptr, colc, Hout, nullptr, nullptr);
    Hin = Hout;
  }

  // fc2 + -log_softmax (MFMA, N=64)
  gemm_kernel<3><<<128, 256, 0, stream>>>((const u16*)Hin, Wt2, fc2b, nullptr, nullptr, nullptr, out);
}

// Round 10
// 304.108 us; speedup vs baseline: 3.7978x; 1.0136x over previous
//
#include <hip/hip_runtime.h>
#include <hip/hip_bf16.h>
#include <cmath>

#define N_NODES 8192
#define NFEAT 512
#define NHID 512
#define NCLASS 64
#define NLAYERS 8
#define CAP 96

typedef __attribute__((ext_vector_type(8))) short bf16x8;
typedef __attribute__((ext_vector_type(4))) float f32x4;
typedef unsigned short u16;

struct Coefs { float cA[8]; float cB[8]; };

__device__ inline float bf2f(short u) {
  union { unsigned int i; float f; } x;
  x.i = ((unsigned int)(u16)u) << 16;
  return x.f;
}
__device__ inline short f2bf(float f) {
  union { float f; unsigned int i; } x;
  x.f = f;
  unsigned int r = x.i + 0x7FFFu + ((x.i >> 16) & 1u);
  return (short)(r >> 16);
}

// ---------------- front: x->bf16 || weight transpose || extract --------------
// Small jobs FIRST so they overlap the extract ramp:
// blocks [0,1024):      x f32->bf16 (16 MB)
// blocks [1024,3584):   weight transpose + GCNII identity fold (9.4 MB)
// blocks [3584,11776):  adjacency extraction (HBM-bound, 256 MB)
__global__ __launch_bounds__(256)
void front_kernel(const float* __restrict__ adj, int* __restrict__ idx,
                  int* __restrict__ cnt, int* __restrict__ colcnt,
                  const float* __restrict__ x, u16* __restrict__ xb,
                  const float* __restrict__ fc1W, const float* __restrict__ convW,
                  const float* __restrict__ fc2W,
                  u16* __restrict__ Wt, u16* __restrict__ Wt2, Coefs co)
{
  __shared__ char smraw[4224];
  const int bid = blockIdx.x;

  if (bid < 1024) {                    // ---- x -> bf16 ----
    const int base = bid * 256 + threadIdx.x;
    const float4* src = (const float4*)x;
    #pragma unroll
    for (int it = 0; it < 4; ++it) {
      const int i = it * (1024 * 256) + base;
      float4 v = src[i];
      ushort4 o;
      o.x = (u16)f2bf(v.x); o.y = (u16)f2bf(v.y);
      o.z = (u16)f2bf(v.z); o.w = (u16)f2bf(v.w);
      ((ushort4*)xb)[i] = o;
    }
    return;
  }

  if (bid < 3584) {                    // ---- weight transpose + fold ----
    // vb in [0,2560): m = vb>>8 (0=fc1, 1..8=conv layer, 9=fc2)
    float (*tile)[33] = (float(*)[33])smraw;
    const int vb = bid - 1024;
    const int m = vb >> 8;
    const int k0 = (vb & 15) * 32, n0 = ((vb >> 4) & 15) * 32;
    if (m == 9 && n0 >= 64) return;
    const int tx = threadIdx.x & 31, ty = threadIdx.x >> 5;  // 32 x 8
    if (m == 9) {
      #pragma unroll
      for (int r = 0; r < 32; r += 8)
        tile[ty + r][tx] = fc2W[(size_t)(k0 + ty + r) * 64 + n0 + tx];
      __syncthreads();
      #pragma unroll
      for (int r = 0; r < 32; r += 8)
        Wt2[(size_t)(n0 + ty + r) * 512 + k0 + tx] = (u16)f2bf(tile[tx][ty + r]);
      return;
    }
    const float* src = (m == 0) ? fc1W : convW + (size_t)(m - 1) * NHID * NHID;
    u16* dst = Wt + (size_t)m * NHID * NHID;
    float cA = 0.f, cB = 1.f;
    if (m >= 1) { cA = co.cA[m - 1]; cB = co.cB[m - 1]; }
    #pragma unroll
    for (int r = 0; r < 32; r += 8)
      tile[ty + r][tx] = src[(size_t)(k0 + ty + r) * NHID + n0 + tx];
    __syncthreads();
    #pragma unroll
    for (int r = 0; r < 32; r += 8) {
      const int krow = k0 + tx, ncol = n0 + ty + r;
      float val = cB * tile[tx][ty + r];
      if (m >= 1 && krow == ncol) val += cA;
      dst[(size_t)ncol * NHID + krow] = (u16)f2bf(val);
    }
    return;
  }

  // ---- extract row ----
  int* s_cnt = (int*)smraw;
  const int i = bid - 3584;
  if (threadIdx.x == 0) *s_cnt = 0;
  __syncthreads();
  const uint4* row = (const uint4*)(adj + (size_t)i * N_NODES);
  for (int c = threadIdx.x; c < N_NODES / 4; c += 256) {
    uint4 v = row[c];
    if ((v.x | v.y | v.z | v.w) == 0u) continue;   // 0.0f bit pattern is 0
    unsigned int vals[4] = {v.x, v.y, v.z, v.w};
    #pragma unroll
    for (int e = 0; e < 4; ++e) {
      if (vals[e] != 0u) {
        int p = atomicAdd(s_cnt, 1);
        if (p < CAP) idx[(size_t)i * CAP + p] = c * 4 + e;
        atomicAdd(&colcnt[c * 4 + e], 1);
      }
    }
  }
  __syncthreads();
  if (threadIdx.x == 0) cnt[i] = min(*s_cnt, CAP);
}

// ---------------- MFMA GEMM, 64x64 tile, BK=64, 2-buf counted-vmcnt ---------
#define AS1 __attribute__((address_space(1)))
#define AS3 __attribute__((address_space(3)))

__device__ inline void load16(const void* g, void* l) {
  __builtin_amdgcn_global_load_lds((const AS1 void*)g, (AS3 void*)l, 16, 0, 0);
}

// MODE 0: v=relu(acc+bias); out0=H0, out1=Hs=dinv*v       [fc1]
// MODE 1: v=relu(acc);      out0=Hs=dinv*v                [layers 0..6]
// MODE 2: v=relu(acc);      out0=H (unscaled)             [layer 7]
// MODE 3: logits=acc+bias -> -log_softmax -> outF (f32)   [fc2, N=64]
// Pipeline per step t (2 bufs, NO vmcnt(0) drain in main loop):
//   B1 s_barrier              : all waves finished READING buf (t+1)&1  (WAR)
//      stage(t+1)             : prefetch into it, flies under compute
//      s_waitcnt vmcnt(4)     : OWN stage(t) 4 loads landed
//   B2 s_barrier              : ALL waves' stage(t) landed              (RAW)
//      compute(t)
// The vmcnt-BEFORE-barrier discipline is what makes cross-wave LDS reads safe
// (vmcnt is per-wave; r9's barrier-then-wait ordering raced and NaN'd).
template<int MODE>
__global__ __launch_bounds__(256, 4)
void gemm_kernel(const u16* __restrict__ A, const u16* __restrict__ Bt,
                 const float* __restrict__ bias, const int* __restrict__ colc,
                 u16* __restrict__ out0, u16* __restrict__ out1,
                 float* __restrict__ outF)
{
  constexpr int K = 512;
  constexpr int N = (MODE == 3) ? NCLASS : 512;
  __shared__ u16 lds[2][2][64 * 64];   // [buf][A/B][tile] = 32 KB
  const int tid = threadIdx.x;
  const int wave = tid >> 6, lane = tid & 63;

  // chunked XCD swizzle (same-A-panel blocks share an XCD's L2)
  const int cpx = gridDim.x >> 3;
  const int logical = (blockIdx.x & 7) * cpx + (blockIdx.x >> 3);
  const int mblk = (MODE == 3) ? logical : (logical >> 3);
  const int nblk = (MODE == 3) ? 0 : (logical & 7);
  const int m0 = mblk * 64, n0 = nblk * 64;

  const int wr = wave >> 1, wc = wave & 1;
  const int lrow = lane & 15, lk = lane >> 4;

  f32x4 acc[2][2];
  #pragma unroll
  for (int a = 0; a < 2; ++a)
    #pragma unroll
    for (int b = 0; b < 2; ++b)
      acc[a][b] = (f32x4){0.f, 0.f, 0.f, 0.f};

  // rows of 64 k = 128 B = 8 chunks of 16 B; XOR swizzle j^(row&7) folded into
  // the per-lane GLOBAL source chunk, LDS dest linear (both-sides rule).
  auto stage = [&](int b, int ks) {
    #pragma unroll
    for (int r = 0; r < 2; ++r) {
      const int c = r * 256 + wave * 64 + lane;   // 512 chunks of 16B per tile
      const int row = c >> 3;
      const int sc = (c & 7) ^ (row & 7);
      load16(A  + (size_t)(m0 + row) * K + ks + sc * 8, &lds[b][0][(r * 256 + wave * 64) * 8]);
      load16(Bt + (size_t)(n0 + row) * K + ks + sc * 8, &lds[b][1][(r * 256 + wave * 64) * 8]);
    }
  };

  stage(0, 0);

  for (int t = 0; t < 8; ++t) {
    asm volatile("s_barrier" ::: "memory");           // B1: WAR on buf (t+1)&1
    if (t + 1 < 8) {
      stage((t + 1) & 1, (t + 1) * 64);
      asm volatile("s_waitcnt vmcnt(4)" ::: "memory"); // own stage(t) landed
    } else {
      asm volatile("s_waitcnt vmcnt(0)" ::: "memory");
    }
    asm volatile("s_barrier" ::: "memory");           // B2: RAW — whole buf t valid
    const int b = t & 1;
    const char* pA = (const char*)lds[b][0];
    const char* pB = (const char*)lds[b][1];
    bf16x8 af[2][2], bfr[2][2];
    #pragma unroll
    for (int mi = 0; mi < 2; ++mi) {
      const int row = wr * 32 + mi * 16 + lrow;
      #pragma unroll
      for (int ks2 = 0; ks2 < 2; ++ks2) {
        const int j = ks2 * 4 + lk;
        af[mi][ks2] = *(const bf16x8*)(pA + row * 128 + ((j ^ (row & 7)) * 16));
      }
    }
    #pragma unroll
    for (int ni = 0; ni < 2; ++ni) {
      const int row = wc * 32 + ni * 16 + lrow;
      #pragma unroll
      for (int ks2 = 0; ks2 < 2; ++ks2) {
        const int j = ks2 * 4 + lk;
        bfr[ni][ks2] = *(const bf16x8*)(pB + row * 128 + ((j ^ (row & 7)) * 16));
      }
    }
    #pragma unroll
    for (int ks2 = 0; ks2 < 2; ++ks2)
      #pragma unroll
      for (int mi = 0; mi < 2; ++mi)
        #pragma unroll
        for (int ni = 0; ni < 2; ++ni)
          acc[mi][ni] = __builtin_amdgcn_mfma_f32_16x16x32_bf16(af[mi][ks2], bfr[ni][ks2], acc[mi][ni], 0, 0, 0);
  }

  if (MODE != 3) {
    #pragma unroll
    for (int mi = 0; mi < 2; ++mi) {
      #pragma unroll
      for (int ni = 0; ni < 2; ++ni) {
        #pragma unroll
        for (int r = 0; r < 4; ++r) {
          const int row = m0 + wr * 32 + mi * 16 + lk * 4 + r;
          const int col = n0 + wc * 32 + ni * 16 + lrow;
          const size_t o = (size_t)row * N + col;
          float v = acc[mi][ni][r];
          if (MODE == 0) {
            v = fmaxf(v + bias[col], 0.f);
            const float di = rsqrtf((float)colc[row] + 1.0f);
            out0[o] = (u16)f2bf(v);                 // H0
            out1[o] = (u16)f2bf(di * v);            // Hs
          } else if (MODE == 1) {
            v = fmaxf(v, 0.f);
            const float di = rsqrtf((float)colc[row] + 1.0f);
            out0[o] = (u16)f2bf(di * v);
          } else {
            v = fmaxf(v, 0.f);
            out0[o] = (u16)f2bf(v);
          }
        }
      }
    }
  } else {
    __syncthreads();
    // stash logits (+bias) in LDS, then per-row softmax with lane = class
    float* Cf = (float*)&lds[0][0][0];              // 64x65 f32
    #pragma unroll
    for (int mi = 0; mi < 2; ++mi)
      #pragma unroll
      for (int ni = 0; ni < 2; ++ni)
        #pragma unroll
        for (int r = 0; r < 4; ++r) {
          const int row = wr * 32 + mi * 16 + lk * 4 + r;
          const int cc = wc * 32 + ni * 16 + lrow;
          if (cc < NCLASS) Cf[row * 65 + cc] = acc[mi][ni][r] + bias[cc];
        }
    __syncthreads();
    #pragma unroll 4
    for (int r = 0; r < 16; ++r) {
      const int row = wave * 16 + r;
      const float v = Cf[row * 65 + lane];
      float mx = v;
      #pragma unroll
      for (int off = 32; off > 0; off >>= 1) mx = fmaxf(mx, __shfl_xor(mx, off));
      float s = __expf(v - mx);
      #pragma unroll
      for (int off = 32; off > 0; off >>= 1) s += __shfl_xor(s, off);
      outF[(size_t)(m0 + row) * NCLASS + lane] = -(v - mx - logf(s));
    }
  }
}

// ---------------- SpMM: IR = 0.9*(P@H) + 0.1*H0, H pre-scaled ---------------
__global__ __launch_bounds__(256)
void spmm_kernel(const u16* __restrict__ Hs, const u16* __restrict__ H0,
                 const int* __restrict__ colc, const int* __restrict__ idx,
                 const int* __restrict__ cnt, u16* __restrict__ IR)
{
  const int wave = threadIdx.x >> 6, lane = threadIdx.x & 63;
  const int i = blockIdx.x * 4 + wave;
  const int c0 = lane * 8;
  const int n = cnt[i];
  int jreg = 0;
  if (lane < n) jreg = idx[(size_t)i * CAP + lane] & (N_NODES - 1);

  float acc[8];
  #pragma unroll
  for (int e = 0; e < 8; ++e) acc[e] = 0.f;

  const int nn = min(n, 64);
  int t = 0;
  for (; t + 8 <= nn; t += 8) {          // 8 gathers in flight
    bf16x8 v[8];
    #pragma unroll
    for (int u = 0; u < 8; ++u) {
      const int j = __shfl(jreg, t + u);
      v[u] = *(const bf16x8*)&Hs[(size_t)j * NHID + c0];
    }
    #pragma unroll
    for (int u = 0; u < 8; ++u)
      #pragma unroll
      for (int e = 0; e < 8; ++e)
        acc[e] += bf2f(v[u][e]);
  }
  for (; t < nn; ++t) {
    const int j = __shfl(jreg, t);
    bf16x8 v = *(const bf16x8*)&Hs[(size_t)j * NHID + c0];
    #pragma unroll
    for (int e = 0; e < 8; ++e) acc[e] += bf2f(v[e]);
  }
  for (; t < n; ++t) {                   // n > 64: essentially never
    const int j = idx[(size_t)i * CAP + t] & (N_NODES - 1);
    bf16x8 v = *(const bf16x8*)&Hs[(size_t)j * NHID + c0];
    #pragma unroll
    for (int e = 0; e < 8; ++e) acc[e] += bf2f(v[e]);
  }

  const float di = rsqrtf((float)colc[i] + 1.0f);
  bf16x8 self = *(const bf16x8*)&Hs[(size_t)i * NHID + c0];
  bf16x8 h0   = *(const bf16x8*)&H0[(size_t)i * NHID + c0];
  bf16x8 ov;
  #pragma unroll
  for (int e = 0; e < 8; ++e) {
    float v = 0.9f * di * (acc[e] + bf2f(self[e])) + 0.1f * bf2f(h0[e]);
    ov[e] = f2bf(v);
  }
  *(bf16x8*)&IR[(size_t)i * NHID + c0] = ov;
}

// ---------------- launch -----------------------------------------------------
extern "C" void kernel_launch(void* const* d_in, const int* in_sizes, int n_in,
                              void* d_out, int out_size, void* d_ws, size_t ws_size,
                              hipStream_t stream)
{
  const float* x     = (const float*)d_in[0];
  const float* adj   = (const float*)d_in[1];
  const float* fc1W  = (const float*)d_in[2];
  const float* fc1b  = (const float*)d_in[3];
  const float* convW = (const float*)d_in[4];
  const float* fc2W  = (const float*)d_in[5];
  const float* fc2b  = (const float*)d_in[6];
  float* out = (float*)d_out;

  char* ws = (char*)d_ws;
  size_t off = 0;
  auto alloc = [&](size_t bytes) -> void* {
    void* p = ws + off;
    off = (off + bytes + 255) & ~(size_t)255;
    return p;
  };
  u16*   xb   = (u16*)alloc((size_t)N_NODES * NFEAT * 2);
  u16*   Wt   = (u16*)alloc((size_t)9 * NHID * NHID * 2);
  u16*   Wt2  = (u16*)alloc((size_t)NCLASS * NHID * 2);
  u16*   H0   = (u16*)alloc((size_t)N_NODES * NHID * 2);
  u16*   HsA  = (u16*)alloc((size_t)N_NODES * NHID * 2);
  u16*   HsB  = (u16*)alloc((size_t)N_NODES * NHID * 2);
  u16*   IR   = (u16*)alloc((size_t)N_NODES * NHID * 2);
  int*   idx  = (int*)alloc((size_t)N_NODES * CAP * 4);
  int*   cnt  = (int*)alloc((size_t)N_NODES * 4);
  int*   colc = (int*)alloc((size_t)N_NODES * 4);

  Coefs co;
  for (int i = 0; i < NLAYERS; ++i) {
    const double beta = log(0.5 / (double)(i + 1) + 1.0);
    co.cA[i] = (float)(1.0 - beta);
    co.cB[i] = (float)beta;
  }

  hipMemsetAsync(colc, 0, (size_t)N_NODES * 4, stream);
  front_kernel<<<1024 + 2560 + 8192, 256, 0, stream>>>(
      adj, idx, cnt, colc, x, xb, fc1W, convW, fc2W, Wt, Wt2, co);

  // fc1: H0 = relu(x@W+b), Hs = dinv*H0
  gemm_kernel<0><<<1024, 256, 0, stream>>>(xb, Wt, fc1b, colc, H0, HsA, nullptr);

  const u16* Hin = HsA;
  for (int i = 0; i < NLAYERS; ++i) {
    spmm_kernel<<<N_NODES / 4, 256, 0, stream>>>(Hin, H0, colc, idx, cnt, IR);
    u16* Hout = (Hin == HsA) ? HsB : HsA;
    if (i < NLAYERS - 1)
      gemm_kernel<1><<<1024, 256, 0, stream>>>(
          IR, Wt + (size_t)(i + 1) * NHID * NHID, nullptr, colc, Hout, nullptr, nullptr);
    else
      gemm_kernel<2><<<1024, 256, 0, stream>>>(
          IR, Wt + (size_t)(i + 1) * NHID * NHID, nullptr, colc, Hout, nullptr, nullptr);
    Hin = Hout;
  }

  // fc2 + -log_softmax (MFMA, N=64)
  gemm_kernel<3><<<128, 256, 0, stream>>>((const u16*)Hin, Wt2, fc2b, nullptr, nullptr, nullptr, out);
}